// Round 6
// baseline (904.837 us; speedup 1.0000x reference)
//
#include <hip/hip_runtime.h>
#include <hip/hip_bf16.h>

// Problem constants (fixed by reference setup_inputs)
#define M_TOK 16384   // B*S = 8*2048
#define DK    4096    // D_IN
#define DN    4096    // D_OUT
#define NE    8       // experts
#define NR    16      // lora rank
#define ERC   128     // E*R
#define RAC   160     // padded router+A columns (8 + 128 + 24 pad)
#define NT_MAIN 128   // base K-tiles of 32
#define NT_ALL  132   // + 4 expert K-tiles

typedef __attribute__((ext_vector_type(8))) short bfrag;   // 8 bf16 (4 VGPRs)
typedef __attribute__((ext_vector_type(4))) float f32x4;   // MFMA acc

__device__ __forceinline__ unsigned short f2bf(float f) {
  unsigned u = __builtin_bit_cast(unsigned, f);
  unsigned rounding = 0x7FFFu + ((u >> 16) & 1u);
  u += rounding;
  return (unsigned short)(u >> 16);
}

__device__ __forceinline__ void load_lds16(const void* g, void* l) {
  __builtin_amdgcn_global_load_lds(
      (__attribute__((address_space(1))) void*)(g),
      (__attribute__((address_space(3))) void*)(l), 16, 0, 0);
}

// ---------- conversion kernels ----------
__global__ void k_cvt(const float* __restrict__ in, unsigned short* __restrict__ out, long n4) {
  long i = (long)blockIdx.x * blockDim.x + threadIdx.x;
  long stride = (long)gridDim.x * blockDim.x;
  for (; i < n4; i += stride) {
    float4 v = reinterpret_cast<const float4*>(in)[i];
    ushort4 o;
    o.x = f2bf(v.x); o.y = f2bf(v.y); o.z = f2bf(v.z); o.w = f2bf(v.w);
    reinterpret_cast<ushort4*>(out)[i] = o;
  }
}

// RA[c][k], c in [0,160): c<8 -> W_router[c][k]; 8<=c<136 -> lora_A[e][k][r]; pad 0
__global__ void k_build_ra(const float* __restrict__ Wr, const float* __restrict__ lA,
                           unsigned short* __restrict__ RA) {
  int idx = blockIdx.x * 256 + threadIdx.x;
  if (idx >= RAC * DK) return;
  int c = idx >> 12;          // /4096
  int k = idx & (DK - 1);
  float v = 0.f;
  if (c < NE) {
    v = Wr[c * DK + k];
  } else if (c < NE + ERC) {
    int er = c - NE;
    int e = er >> 4, r = er & 15;
    v = lA[((long)e * DK + k) * NR + r];
  }
  RA[idx] = f2bf(v);
}

// BT[n][kp] = lora_B[kp/16][kp%16][n]  -> [DN][128] bf16
__global__ void k_build_bt(const float* __restrict__ lB, unsigned short* __restrict__ BT) {
  int idx = blockIdx.x * 256 + threadIdx.x;
  if (idx >= DN * ERC) return;
  int n = idx >> 7;
  int kp = idx & 127;
  BT[idx] = f2bf(lB[(long)kp * DN + n]);
}

// ---------- small GEMM: H[t][c] = sum_k Xb[t][k]*RA[c][k], c in [0,160) ----------
__global__ __launch_bounds__(256, 2)
void k_gemm_small(const unsigned short* __restrict__ X, const unsigned short* __restrict__ RA,
                  float* __restrict__ H) {
  __shared__ unsigned short At[64 * 64];
  __shared__ unsigned short Bt[RAC * 64];
  int m0 = blockIdx.x * 64;
  int tid = threadIdx.x;
  int lane = tid & 63, wid = tid >> 6;
  int wr = wid >> 1, wc = wid & 1;      // 2x2 waves; wave tile 32 x 80
  int l16 = lane & 15, lhi = lane >> 4;
  f32x4 acc[2][5] = {};
  int byteoff = tid * 16;
  for (int k0 = 0; k0 < DK; k0 += 64) {
#pragma unroll
    for (int r = 0; r < 2; r++) {
      int off = r * 4096 + byteoff;
      int row = off >> 7, colb = off & 127;
      load_lds16((const char*)X + ((long)(m0 + row) * DK + k0) * 2 + colb, (char*)At + off);
    }
#pragma unroll
    for (int r = 0; r < 5; r++) {
      int off = r * 4096 + byteoff;
      int row = off >> 7, colb = off & 127;
      load_lds16((const char*)RA + ((long)row * DK + k0) * 2 + colb, (char*)Bt + off);
    }
    __syncthreads();
#pragma unroll
    for (int kk = 0; kk < 2; kk++) {
      bfrag a[2], b[5];
#pragma unroll
      for (int m = 0; m < 2; m++)
        a[m] = *(const bfrag*)&At[(wr * 32 + m * 16 + l16) * 64 + kk * 32 + lhi * 8];
#pragma unroll
      for (int n = 0; n < 5; n++)
        b[n] = *(const bfrag*)&Bt[(wc * 80 + n * 16 + l16) * 64 + kk * 32 + lhi * 8];
#pragma unroll
      for (int m = 0; m < 2; m++)
#pragma unroll
        for (int n = 0; n < 5; n++)
          acc[m][n] = __builtin_amdgcn_mfma_f32_16x16x32_bf16(a[m], b[n], acc[m][n], 0, 0, 0);
    }
    __syncthreads();
  }
#pragma unroll
  for (int m = 0; m < 2; m++)
#pragma unroll
    for (int n = 0; n < 5; n++) {
      int col = wc * 80 + n * 16 + l16;
      int row = m0 + wr * 32 + m * 16 + lhi * 4;
#pragma unroll
      for (int j = 0; j < 4; j++)
        H[(long)(row + j) * RAC + col] = acc[m][n][j];
    }
}

// ---------- sparsemax + weight application ----------
__global__ void k_router(const float* __restrict__ H, const float* __restrict__ b_router,
                         unsigned short* __restrict__ G) {
  int t = blockIdx.x * blockDim.x + threadIdx.x;
  if (t >= M_TOK) return;
  const float* row = H + (long)t * RAC;
  float z[NE], zs[NE];
#pragma unroll
  for (int e = 0; e < NE; e++) { z[e] = row[e] + b_router[e]; zs[e] = z[e]; }
#pragma unroll
  for (int i = 1; i < NE; i++) {
    float key = zs[i];
    int j = i - 1;
    while (j >= 0 && zs[j] < key) { zs[j + 1] = zs[j]; j--; }
    zs[j + 1] = key;
  }
  float cums[NE];
  float cum = 0.f;
#pragma unroll
  for (int j = 0; j < NE; j++) { cum += zs[j]; cums[j] = cum; }
  int kz = 0;
#pragma unroll
  for (int j = 0; j < NE; j++)
    if (1.f + (float)(j + 1) * zs[j] > cums[j]) kz = j + 1;
  float tau = (cums[kz - 1] - 1.f) / (float)kz;
#pragma unroll
  for (int e = 0; e < NE; e++) {
    float we = fmaxf(z[e] - tau, 0.f);
#pragma unroll
    for (int r = 0; r < NR; r++)
      G[(long)t * ERC + e * NR + r] = f2bf(we * row[NE + e * NR + r]);
  }
}

// ---------- main GEMM: 256x256 tile, BK=32, 4-deep ring, 1 barrier/tile ------
// out = Xb @ Wb^T + bias + G @ BT^T, fused as 128 + 4 K-tiles of 32.
// ONE boundary sync per K-tile: s_waitcnt vmcnt(8) + s_barrier certifies slot
// t+1 (stages for t+2,t+3 are the 8 newest outstanding). NO intra-tile
// barriers and NO explicit lgkmcnt drains: slot safety never needs them
// (stage targets slot t+3, disjoint from live slots t..t+2), and the compiler
// emits fine-grained counted lgkmcnt between ds_read and MFMA (m97 asm), so
// one wave's MFMA cluster overlaps other waves' LDS drains instead of the
// CU-wide {all-drain -> all-MFMA} phase-lock that barrier+lgkm0 enforced.
// T2 swizzle (rule #21 both-sides): source slot pre-permuted by
// ((tid&3)^((tid>>3)&3)); read slot = lhi ^ ((l16>>1)&3). Conflict-free.
struct KtArgs {
  const unsigned short *pXA0, *pXA1, *pWB0, *pWB1, *pGA0, *pGA1, *pTB0, *pTB1;
  int soffA0, soffA1, soffB0, soffB1;   // element offsets within a ring slot
  int wr, wc, l16, swslot;              // swslot in shorts
};

template<bool STAGE, int VMB>
__device__ __forceinline__ void ktile_body(int t, unsigned short* lds, const KtArgs& A,
                                           f32x4 (&acc)[8][4]) {
  unsigned short* s = lds + (t & 3) * 16384;
  bfrag bfr[4], al[4], ah[4];
  // issue lo-cluster reads first (B-frags + A-lo), then hi (A-hi): hi queues
  // behind lo in the LDS pipe and drains under the lo-MFMA cluster.
#pragma unroll
  for (int n = 0; n < 4; n++)
    bfr[n] = *(const bfrag*)&s[8192 + (A.wc * 64 + n * 16 + A.l16) * 32 + A.swslot];
#pragma unroll
  for (int m = 0; m < 4; m++)
    al[m] = *(const bfrag*)&s[(A.wr * 128 + m * 16 + A.l16) * 32 + A.swslot];
#pragma unroll
  for (int m = 0; m < 4; m++)
    ah[m] = *(const bfrag*)&s[(A.wr * 128 + 64 + m * 16 + A.l16) * 32 + A.swslot];
  if constexpr (STAGE) {
    int u = t + 3;
    unsigned short* d = lds + (u & 3) * 16384;
    if (u < NT_MAIN) {
      load_lds16(A.pXA0 + (long)u * 32, d + A.soffA0);
      load_lds16(A.pXA1 + (long)u * 32, d + A.soffA1);
      load_lds16(A.pWB0 + (long)u * 32, d + A.soffB0);
      load_lds16(A.pWB1 + (long)u * 32, d + A.soffB1);
    } else {
      long v = u - NT_MAIN;
      load_lds16(A.pGA0 + v * 32, d + A.soffA0);
      load_lds16(A.pGA1 + v * 32, d + A.soffA1);
      load_lds16(A.pTB0 + v * 32, d + A.soffB0);
      load_lds16(A.pTB1 + v * 32, d + A.soffB1);
    }
  }
  // lo cluster (compiler inserts counted lgkm waits for bfr/al only)
  __builtin_amdgcn_s_setprio(1);
#pragma unroll
  for (int m = 0; m < 4; m++)
#pragma unroll
    for (int n = 0; n < 4; n++)
      acc[m][n] = __builtin_amdgcn_mfma_f32_16x16x32_bf16(al[m], bfr[n], acc[m][n], 0, 0, 0);
  __builtin_amdgcn_s_setprio(0);
  // hi cluster (waits for ah, which drained under the lo cluster)
  __builtin_amdgcn_s_setprio(1);
#pragma unroll
  for (int m = 0; m < 4; m++)
#pragma unroll
    for (int n = 0; n < 4; n++)
      acc[4 + m][n] = __builtin_amdgcn_mfma_f32_16x16x32_bf16(ah[m], bfr[n], acc[4 + m][n], 0, 0, 0);
  __builtin_amdgcn_s_setprio(0);
  // ---- boundary: certify slot t+1 for next tile's reads ----
  if constexpr (VMB == 8)      asm volatile("s_waitcnt vmcnt(8)\n\ts_barrier" ::: "memory");
  else if constexpr (VMB == 4) asm volatile("s_waitcnt vmcnt(4)\n\ts_barrier" ::: "memory");
  else if constexpr (VMB == 0) asm volatile("s_waitcnt vmcnt(0)\n\ts_barrier" ::: "memory");
  // VMB < 0: last tile, no boundary needed
}

__global__ __launch_bounds__(512, 2)
void k_gemm_main(const unsigned short* __restrict__ X, const unsigned short* __restrict__ W,
                 const unsigned short* __restrict__ G, const unsigned short* __restrict__ BT,
                 const float* __restrict__ bias, float* __restrict__ out) {
  // 4 ring slots x (A[256][32] + B[256][32]) bf16 = 4 x 32 KiB = 128 KiB
  __shared__ unsigned short lds[4 * 16384];
  int bid = blockIdx.x;
  // XCD-aware swizzle: 1024 workgroups, 8 XCDs -> contiguous chunks of 128 per XCD
  int swz = (bid & 7) * 128 + (bid >> 3);
  int bm = swz >> 4, bn = swz & 15;
  int m0 = bm * 256, n0 = bn * 256;
  int tid = threadIdx.x;
  int lane = tid & 63, wid = tid >> 6;

  KtArgs A;
  A.wr = wid >> 2; A.wc = wid & 3;      // 2x4 waves; wave tile 128 x 64
  A.l16 = lane & 15;
  int lhi = lane >> 4;
  A.swslot = (lhi ^ ((A.l16 >> 1) & 3)) * 8;      // read-side swizzle (shorts)
  // staging: thread tid owns LDS (row=tid>>2, slot=tid&3); source slot pre-swizzled
  int r0 = tid >> 2;
  int c8 = (((tid & 3) ^ ((tid >> 3) & 3)) * 8);  // swizzled source column (shorts)
  A.pXA0 = X + (long)(m0 + r0) * DK + c8;
  A.pXA1 = X + (long)(m0 + 128 + r0) * DK + c8;
  A.pWB0 = W + (long)(n0 + r0) * DK + c8;
  A.pWB1 = W + (long)(n0 + 128 + r0) * DK + c8;
  A.pGA0 = G + (long)(m0 + r0) * ERC + c8;
  A.pGA1 = G + (long)(m0 + 128 + r0) * ERC + c8;
  A.pTB0 = BT + (long)(n0 + r0) * ERC + c8;
  A.pTB1 = BT + (long)(n0 + 128 + r0) * ERC + c8;
  A.soffA0 = tid * 8;
  A.soffA1 = 4096 + tid * 8;
  A.soffB0 = 8192 + tid * 8;
  A.soffB1 = 12288 + tid * 8;

  f32x4 acc[8][4] = {};

  // prologue: stage tiles 0,1,2 (all base-path); certify slot 0
#pragma unroll
  for (int u = 0; u < 3; u++) {
    unsigned short* d = lds + u * 16384;
    load_lds16(A.pXA0 + (long)u * 32, d + A.soffA0);
    load_lds16(A.pXA1 + (long)u * 32, d + A.soffA1);
    load_lds16(A.pWB0 + (long)u * 32, d + A.soffB0);
    load_lds16(A.pWB1 + (long)u * 32, d + A.soffB1);
  }
  asm volatile("s_waitcnt vmcnt(8)\n\ts_barrier" ::: "memory");

  for (int t = 0; t <= 128; t++)
    ktile_body<true, 8>(t, lds, A, acc);
  ktile_body<false, 4>(129, lds, A, acc);
  ktile_body<false, 0>(130, lds, A, acc);
  ktile_body<false, -1>(131, lds, A, acc);

  // epilogue: bias + f32 store
#pragma unroll
  for (int n = 0; n < 4; n++) {
    int col = n0 + A.wc * 64 + n * 16 + A.l16;
    float bv = bias[col];
#pragma unroll
    for (int m = 0; m < 8; m++) {
      int row = m0 + A.wr * 128 + m * 16 + lhi * 4;
#pragma unroll
      for (int j = 0; j < 4; j++)
        out[(long)(row + j) * DN + col] = acc[m][n][j] + bv;
    }
  }
}

extern "C" void kernel_launch(void* const* d_in, const int* in_sizes, int n_in,
                              void* d_out, int out_size, void* d_ws, size_t ws_size,
                              hipStream_t stream) {
  const float* x        = (const float*)d_in[0];
  const float* W_base   = (const float*)d_in[1];
  const float* b_base   = (const float*)d_in[2];
  const float* W_router = (const float*)d_in[3];
  const float* b_router = (const float*)d_in[4];
  const float* lora_A   = (const float*)d_in[5];
  const float* lora_B   = (const float*)d_in[6];
  float* out = (float*)d_out;

  char* ws = (char*)d_ws;
  unsigned short* Xb = (unsigned short*)ws;                       // 134217728 B
  unsigned short* Wb = (unsigned short*)(ws + 134217728L);        // 33554432 B
  unsigned short* RA = (unsigned short*)(ws + 167772160L);        // 1310720 B
  unsigned short* BT = (unsigned short*)(ws + 169082880L);        // 1048576 B
  float*          H  = (float*)(ws + 170131456L);                 // 10485760 B
  unsigned short* G  = (unsigned short*)(ws + 180617216L);        // 4194304 B

  hipLaunchKernelGGL(k_cvt, dim3(2048), dim3(256), 0, stream, x, Xb, (long)M_TOK * DK / 4);
  hipLaunchKernelGGL(k_cvt, dim3(2048), dim3(256), 0, stream, W_base, Wb, (long)DN * DK / 4);
  hipLaunchKernelGGL(k_build_ra, dim3((RAC * DK + 255) / 256), dim3(256), 0, stream,
                     W_router, lora_A, RA);
  hipLaunchKernelGGL(k_build_bt, dim3((DN * ERC + 255) / 256), dim3(256), 0, stream, lora_B, BT);
  hipLaunchKernelGGL(k_gemm_small, dim3(M_TOK / 64), dim3(256), 0, stream, Xb, RA, H);
  hipLaunchKernelGGL(k_router, dim3(M_TOK / 256), dim3(256), 0, stream, H, b_router, G);
  hipLaunchKernelGGL(k_gemm_main, dim3((M_TOK / 256) * (DN / 256)), dim3(512), 0, stream,
                     Xb, Wb, G, BT, b_base, out);
}

// Round 7
// 858.207 us; speedup vs baseline: 1.0543x; 1.0543x over previous
//
#include <hip/hip_runtime.h>
#include <hip/hip_bf16.h>

// Problem constants (fixed by reference setup_inputs)
#define M_TOK 16384   // B*S = 8*2048
#define DK    4096    // D_IN
#define DN    4096    // D_OUT
#define NE    8       // experts
#define NR    16      // lora rank
#define ERC   128     // E*R
#define RAC   160     // padded router+A columns (8 + 128 + 24 pad)
#define NT_MAIN 128   // base K-tiles of 32
#define NT_ALL  132   // + 4 expert K-tiles

typedef __attribute__((ext_vector_type(8))) short bfrag;   // 8 bf16 (4 VGPRs)
typedef __attribute__((ext_vector_type(4))) float f32x4;   // MFMA acc

__device__ __forceinline__ unsigned short f2bf(float f) {
  unsigned u = __builtin_bit_cast(unsigned, f);
  unsigned rounding = 0x7FFFu + ((u >> 16) & 1u);
  u += rounding;
  return (unsigned short)(u >> 16);
}

__device__ __forceinline__ void load_lds16(const void* g, void* l) {
  __builtin_amdgcn_global_load_lds(
      (__attribute__((address_space(1))) void*)(g),
      (__attribute__((address_space(3))) void*)(l), 16, 0, 0);
}

// ---------- conversion kernels ----------
__global__ void k_cvt(const float* __restrict__ in, unsigned short* __restrict__ out, long n4) {
  long i = (long)blockIdx.x * blockDim.x + threadIdx.x;
  long stride = (long)gridDim.x * blockDim.x;
  for (; i < n4; i += stride) {
    float4 v = reinterpret_cast<const float4*>(in)[i];
    ushort4 o;
    o.x = f2bf(v.x); o.y = f2bf(v.y); o.z = f2bf(v.z); o.w = f2bf(v.w);
    reinterpret_cast<ushort4*>(out)[i] = o;
  }
}

// RA[c][k], c in [0,160): c<8 -> W_router[c][k]; 8<=c<136 -> lora_A[e][k][r]; pad 0
__global__ void k_build_ra(const float* __restrict__ Wr, const float* __restrict__ lA,
                           unsigned short* __restrict__ RA) {
  int idx = blockIdx.x * 256 + threadIdx.x;
  if (idx >= RAC * DK) return;
  int c = idx >> 12;          // /4096
  int k = idx & (DK - 1);
  float v = 0.f;
  if (c < NE) {
    v = Wr[c * DK + k];
  } else if (c < NE + ERC) {
    int er = c - NE;
    int e = er >> 4, r = er & 15;
    v = lA[((long)e * DK + k) * NR + r];
  }
  RA[idx] = f2bf(v);
}

// BT[n][kp] = lora_B[kp/16][kp%16][n]  -> [DN][128] bf16
__global__ void k_build_bt(const float* __restrict__ lB, unsigned short* __restrict__ BT) {
  int idx = blockIdx.x * 256 + threadIdx.x;
  if (idx >= DN * ERC) return;
  int n = idx >> 7;
  int kp = idx & 127;
  BT[idx] = f2bf(lB[(long)kp * DN + n]);
}

// ---------- small GEMM: H[t][c] = sum_k Xb[t][k]*RA[c][k], c in [0,160) ----------
__global__ __launch_bounds__(256, 2)
void k_gemm_small(const unsigned short* __restrict__ X, const unsigned short* __restrict__ RA,
                  float* __restrict__ H) {
  __shared__ unsigned short At[64 * 64];
  __shared__ unsigned short Bt[RAC * 64];
  int m0 = blockIdx.x * 64;
  int tid = threadIdx.x;
  int lane = tid & 63, wid = tid >> 6;
  int wr = wid >> 1, wc = wid & 1;      // 2x2 waves; wave tile 32 x 80
  int l16 = lane & 15, lhi = lane >> 4;
  f32x4 acc[2][5] = {};
  int byteoff = tid * 16;
  for (int k0 = 0; k0 < DK; k0 += 64) {
#pragma unroll
    for (int r = 0; r < 2; r++) {
      int off = r * 4096 + byteoff;
      int row = off >> 7, colb = off & 127;
      load_lds16((const char*)X + ((long)(m0 + row) * DK + k0) * 2 + colb, (char*)At + off);
    }
#pragma unroll
    for (int r = 0; r < 5; r++) {
      int off = r * 4096 + byteoff;
      int row = off >> 7, colb = off & 127;
      load_lds16((const char*)RA + ((long)row * DK + k0) * 2 + colb, (char*)Bt + off);
    }
    __syncthreads();
#pragma unroll
    for (int kk = 0; kk < 2; kk++) {
      bfrag a[2], b[5];
#pragma unroll
      for (int m = 0; m < 2; m++)
        a[m] = *(const bfrag*)&At[(wr * 32 + m * 16 + l16) * 64 + kk * 32 + lhi * 8];
#pragma unroll
      for (int n = 0; n < 5; n++)
        b[n] = *(const bfrag*)&Bt[(wc * 80 + n * 16 + l16) * 64 + kk * 32 + lhi * 8];
#pragma unroll
      for (int m = 0; m < 2; m++)
#pragma unroll
        for (int n = 0; n < 5; n++)
          acc[m][n] = __builtin_amdgcn_mfma_f32_16x16x32_bf16(a[m], b[n], acc[m][n], 0, 0, 0);
    }
    __syncthreads();
  }
#pragma unroll
  for (int m = 0; m < 2; m++)
#pragma unroll
    for (int n = 0; n < 5; n++) {
      int col = wc * 80 + n * 16 + l16;
      int row = m0 + wr * 32 + m * 16 + lhi * 4;
#pragma unroll
      for (int j = 0; j < 4; j++)
        H[(long)(row + j) * RAC + col] = acc[m][n][j];
    }
}

// ---------- sparsemax + weight application ----------
__global__ void k_router(const float* __restrict__ H, const float* __restrict__ b_router,
                         unsigned short* __restrict__ G) {
  int t = blockIdx.x * blockDim.x + threadIdx.x;
  if (t >= M_TOK) return;
  const float* row = H + (long)t * RAC;
  float z[NE], zs[NE];
#pragma unroll
  for (int e = 0; e < NE; e++) { z[e] = row[e] + b_router[e]; zs[e] = z[e]; }
#pragma unroll
  for (int i = 1; i < NE; i++) {
    float key = zs[i];
    int j = i - 1;
    while (j >= 0 && zs[j] < key) { zs[j + 1] = zs[j]; j--; }
    zs[j + 1] = key;
  }
  float cums[NE];
  float cum = 0.f;
#pragma unroll
  for (int j = 0; j < NE; j++) { cum += zs[j]; cums[j] = cum; }
  int kz = 0;
#pragma unroll
  for (int j = 0; j < NE; j++)
    if (1.f + (float)(j + 1) * zs[j] > cums[j]) kz = j + 1;
  float tau = (cums[kz - 1] - 1.f) / (float)kz;
#pragma unroll
  for (int e = 0; e < NE; e++) {
    float we = fmaxf(z[e] - tau, 0.f);
#pragma unroll
    for (int r = 0; r < NR; r++)
      G[(long)t * ERC + e * NR + r] = f2bf(we * row[NE + e * NR + r]);
  }
}

// ---------- main GEMM: 128x256 block, 4 waves, BK=32, 3-slot ring ------------
// out = Xb @ Wb^T + bias + G @ BT^T, fused as 128 + 4 K-tiles of 32.
// TWO blocks per CU (72 KiB LDS each): independent barriers let the two
// blocks drift into anti-phase, so one block's MFMA clusters overlap the
// other's LDS drains (m114: co-resident waves co-schedule across pipes) --
// breaking the intra-block {all-drain}->{all-MFMA} phase-lock that capped
// the 512-thread single-block variant at MfmaUtil 46%.
// Per-tile rhythm (R5-proven): ph0 {8 ds_read + 4 stage, bar, lgkm0, 16 MFMA},
// ph1 {4 ds_read + 2 stage, bar, lgkm0, 16 MFMA}, boundary vmcnt(6)+bar
// (counted: tile t+2's 6 loads are the newest outstanding -> certifies t+1).
// T2 swizzle (rule #21 both-sides): source slot pre-permuted by
// ((tid&3)^((tid>>3)&3)); read slot = lhi ^ ((l16>>1)&3). Measured 0 conflicts.
struct KtArgs {
  const unsigned short *pXA, *pWB, *pGA, *pTB;
  int dA, dB;            // stage dest offsets (shorts) within a slot
  int aBase, bBase;      // read base offsets (shorts) within a slot
};

template<bool STG, int VMB>
__device__ __forceinline__ void tile_body(int t, int s, int su, unsigned short* lds,
                                          const KtArgs& A, f32x4 (&acc)[4][8]) {
  unsigned short* L = lds + s * 12288;
  unsigned short* D = lds + su * 12288;
  bfrag a[4], bl[4], bh[4];
  // ---- ph0: read A(4) + B-lo(4); stage A(t+2) 2 loads + B(t+2) rounds 0-1 ----
#pragma unroll
  for (int mf = 0; mf < 4; mf++)
    a[mf] = *(const bfrag*)&L[A.aBase + mf * 512];
#pragma unroll
  for (int nf = 0; nf < 4; nf++)
    bl[nf] = *(const bfrag*)&L[A.bBase + nf * 512];
  if constexpr (STG) {
    int u = t + 2;
    if (u < NT_MAIN) {
      load_lds16(A.pXA + (long)u * 32, D + A.dA);
      load_lds16(A.pXA + (long)64 * DK + (long)u * 32, D + 2048 + A.dA);
      load_lds16(A.pWB + (long)u * 32, D + A.dB);
      load_lds16(A.pWB + (long)64 * DK + (long)u * 32, D + 2048 + A.dB);
    } else {
      long v = (long)(u - NT_MAIN) * 32;
      load_lds16(A.pGA + v, D + A.dA);
      load_lds16(A.pGA + (long)64 * ERC + v, D + 2048 + A.dA);
      load_lds16(A.pTB + v, D + A.dB);
      load_lds16(A.pTB + (long)64 * ERC + v, D + 2048 + A.dB);
    }
  }
  asm volatile("s_barrier\n\ts_waitcnt lgkmcnt(0)" ::: "memory");
  __builtin_amdgcn_sched_barrier(0);
  __builtin_amdgcn_s_setprio(1);
#pragma unroll
  for (int mf = 0; mf < 4; mf++)
#pragma unroll
    for (int nf = 0; nf < 4; nf++)
      acc[mf][nf] = __builtin_amdgcn_mfma_f32_16x16x32_bf16(a[mf], bl[nf], acc[mf][nf], 0, 0, 0);
  __builtin_amdgcn_s_setprio(0);
  // ---- ph1: read B-hi(4); stage B(t+2) rounds 2-3 ----
#pragma unroll
  for (int nf = 0; nf < 4; nf++)
    bh[nf] = *(const bfrag*)&L[A.bBase + (4 + nf) * 512];
  if constexpr (STG) {
    int u = t + 2;
    if (u < NT_MAIN) {
      load_lds16(A.pWB + (long)128 * DK + (long)u * 32, D + 4096 + A.dB);
      load_lds16(A.pWB + (long)192 * DK + (long)u * 32, D + 6144 + A.dB);
    } else {
      long v = (long)(u - NT_MAIN) * 32;
      load_lds16(A.pTB + (long)128 * ERC + v, D + 4096 + A.dB);
      load_lds16(A.pTB + (long)192 * ERC + v, D + 6144 + A.dB);
    }
  }
  asm volatile("s_barrier\n\ts_waitcnt lgkmcnt(0)" ::: "memory");
  __builtin_amdgcn_sched_barrier(0);
  __builtin_amdgcn_s_setprio(1);
#pragma unroll
  for (int mf = 0; mf < 4; mf++)
#pragma unroll
    for (int nf = 0; nf < 4; nf++)
      acc[mf][4 + nf] = __builtin_amdgcn_mfma_f32_16x16x32_bf16(a[mf], bh[nf], acc[mf][4 + nf], 0, 0, 0);
  __builtin_amdgcn_s_setprio(0);
  // ---- boundary: certify slot t+1 for next tile's reads ----
  if constexpr (VMB == 6)      asm volatile("s_waitcnt vmcnt(6)\n\ts_barrier" ::: "memory");
  else if constexpr (VMB == 0) asm volatile("s_waitcnt vmcnt(0)\n\ts_barrier" ::: "memory");
  // VMB < 0: last tile, no boundary needed
}

__global__ __launch_bounds__(256, 2)
void k_gemm_main(const unsigned short* __restrict__ X, const unsigned short* __restrict__ W,
                 const unsigned short* __restrict__ G, const unsigned short* __restrict__ BT,
                 const float* __restrict__ bias, float* __restrict__ out) {
  // 3 ring slots x (A[128][32] + B[256][32]) bf16 = 3 x 24 KiB = 72 KiB
  __shared__ unsigned short lds[3 * 12288];
  int bid = blockIdx.x;
  // XCD-aware swizzle: 2048 workgroups, 8 XCDs -> contiguous chunks of 256 per XCD.
  // Co-resident blocks (bid, bid+8) get adjacent swz -> same bm, adjacent bn
  // -> they share the X panel (L2-friendly).
  int swz = (bid & 7) * 256 + (bid >> 3);
  int bm = swz >> 4, bn = swz & 15;       // 128 m-tiles x 16 n-tiles
  int m0 = bm * 128, n0 = bn * 256;
  int tid = threadIdx.x;
  int lane = tid & 63, wid = tid >> 6;
  int wrr = wid >> 1, wcc = wid & 1;      // 2x2 waves; wave tile 64 x 128
  int l16 = lane & 15, lhi = lane >> 4;
  int swslot = (lhi ^ ((l16 >> 1) & 3)) * 8;      // read-side swizzle (shorts)
  int r0 = tid >> 2;
  int g8 = (((tid & 3) ^ ((tid >> 3) & 3)) * 8);  // swizzled source column (shorts)

  KtArgs A;
  A.pXA = X + (long)(m0 + r0) * DK + g8;
  A.pWB = W + (long)(n0 + r0) * DK + g8;
  A.pGA = G + (long)(m0 + r0) * ERC + g8;
  A.pTB = BT + (long)(n0 + r0) * ERC + g8;
  A.dA = tid * 8;               // A dest: rows r0 + 64j, 2 rounds
  A.dB = 4096 + tid * 8;        // B dest: rows r0 + 64j, 4 rounds
  A.aBase = (wrr * 64 + l16) * 32 + swslot;
  A.bBase = 4096 + (wcc * 128 + l16) * 32 + swslot;

  f32x4 acc[4][8] = {};

  // prologue: stage tiles 0 (slot 0) and 1 (slot 1); certify tile 0
#pragma unroll
  for (int u = 0; u < 2; u++) {
    unsigned short* D = lds + u * 12288;
    load_lds16(A.pXA + (long)u * 32, D + A.dA);
    load_lds16(A.pXA + (long)64 * DK + (long)u * 32, D + 2048 + A.dA);
#pragma unroll
    for (int j = 0; j < 4; j++)
      load_lds16(A.pWB + (long)(64 * j) * DK + (long)u * 32, D + A.dB + j * 2048);
  }
  asm volatile("s_waitcnt vmcnt(6)\n\ts_barrier" ::: "memory");

  int s = 0, su = 2;
  for (int t = 0; t < 130; t++) {
    tile_body<true, 6>(t, s, su, lds, A, acc);
    s = (s == 2) ? 0 : s + 1;
    su = (su == 2) ? 0 : su + 1;
  }
  tile_body<false, 0>(130, s, su, lds, A, acc);
  s = (s == 2) ? 0 : s + 1;
  tile_body<false, -1>(131, s, su, lds, A, acc);

  // epilogue: bias + f32 store
#pragma unroll
  for (int nf = 0; nf < 8; nf++) {
    int col = n0 + wcc * 128 + nf * 16 + l16;
    float bv = bias[col];
#pragma unroll
    for (int mf = 0; mf < 4; mf++) {
      int row = m0 + wrr * 64 + mf * 16 + lhi * 4;
#pragma unroll
      for (int j = 0; j < 4; j++)
        out[(long)(row + j) * DN + col] = acc[mf][nf][j] + bv;
    }
  }
}

extern "C" void kernel_launch(void* const* d_in, const int* in_sizes, int n_in,
                              void* d_out, int out_size, void* d_ws, size_t ws_size,
                              hipStream_t stream) {
  const float* x        = (const float*)d_in[0];
  const float* W_base   = (const float*)d_in[1];
  const float* b_base   = (const float*)d_in[2];
  const float* W_router = (const float*)d_in[3];
  const float* b_router = (const float*)d_in[4];
  const float* lora_A   = (const float*)d_in[5];
  const float* lora_B   = (const float*)d_in[6];
  float* out = (float*)d_out;

  char* ws = (char*)d_ws;
  unsigned short* Xb = (unsigned short*)ws;                       // 134217728 B
  unsigned short* Wb = (unsigned short*)(ws + 134217728L);        // 33554432 B
  unsigned short* RA = (unsigned short*)(ws + 167772160L);        // 1310720 B
  unsigned short* BT = (unsigned short*)(ws + 169082880L);        // 1048576 B
  float*          H  = (float*)(ws + 170131456L);                 // 10485760 B
  unsigned short* G  = (unsigned short*)(ws + 180617216L);        // 4194304 B

  hipLaunchKernelGGL(k_cvt, dim3(2048), dim3(256), 0, stream, x, Xb, (long)M_TOK * DK / 4);
  hipLaunchKernelGGL(k_cvt, dim3(2048), dim3(256), 0, stream, W_base, Wb, (long)DN * DK / 4);
  hipLaunchKernelGGL(k_build_ra, dim3((RAC * DK + 255) / 256), dim3(256), 0, stream,
                     W_router, lora_A, RA);
  hipLaunchKernelGGL(k_build_bt, dim3((DN * ERC + 255) / 256), dim3(256), 0, stream, lora_B, BT);
  hipLaunchKernelGGL(k_gemm_small, dim3(M_TOK / 64), dim3(256), 0, stream, Xb, RA, H);
  hipLaunchKernelGGL(k_router, dim3(M_TOK / 256), dim3(256), 0, stream, H, b_router, G);
  hipLaunchKernelGGL(k_gemm_main, dim3((M_TOK / 128) * (DN / 256)), dim3(256), 0, stream,
                     Xb, Wb, G, BT, b_base, out);
}

// Round 9
// 674.013 us; speedup vs baseline: 1.3425x; 1.2733x over previous
//
#include <hip/hip_runtime.h>
#include <hip/hip_bf16.h>

// Problem constants (fixed by reference setup_inputs)
#define M_TOK 16384   // B*S = 8*2048
#define DK    4096    // D_IN
#define DN    4096    // D_OUT
#define NE    8       // experts
#define NR    16      // lora rank
#define ERC   128     // E*R
#define RAC   160     // padded router+A columns (8 + 128 + 24 pad)
#define NT_MAIN 128   // base K-tiles of 32
#define NT_ALL  132   // + 4 expert K-tiles

typedef __attribute__((ext_vector_type(8))) short bfrag;   // 8 bf16 (4 VGPRs)
typedef __attribute__((ext_vector_type(4))) float f32x4;   // MFMA acc

__device__ __forceinline__ unsigned short f2bf(float f) {
  unsigned u = __builtin_bit_cast(unsigned, f);
  unsigned rounding = 0x7FFFu + ((u >> 16) & 1u);
  u += rounding;
  return (unsigned short)(u >> 16);
}

__device__ __forceinline__ void load_lds16(const void* g, void* l) {
  __builtin_amdgcn_global_load_lds(
      (__attribute__((address_space(1))) void*)(g),
      (__attribute__((address_space(3))) void*)(l), 16, 0, 0);
}

// ---------- conversion kernels ----------
__global__ void k_cvt(const float* __restrict__ in, unsigned short* __restrict__ out, long n4) {
  long i = (long)blockIdx.x * blockDim.x + threadIdx.x;
  long stride = (long)gridDim.x * blockDim.x;
  for (; i < n4; i += stride) {
    float4 v = reinterpret_cast<const float4*>(in)[i];
    ushort4 o;
    o.x = f2bf(v.x); o.y = f2bf(v.y); o.z = f2bf(v.z); o.w = f2bf(v.w);
    reinterpret_cast<ushort4*>(out)[i] = o;
  }
}

// RA[c][k], c in [0,160): c<8 -> W_router[c][k]; 8<=c<136 -> lora_A[e][k][r]; pad 0
__global__ void k_build_ra(const float* __restrict__ Wr, const float* __restrict__ lA,
                           unsigned short* __restrict__ RA) {
  int idx = blockIdx.x * 256 + threadIdx.x;
  if (idx >= RAC * DK) return;
  int c = idx >> 12;          // /4096
  int k = idx & (DK - 1);
  float v = 0.f;
  if (c < NE) {
    v = Wr[c * DK + k];
  } else if (c < NE + ERC) {
    int er = c - NE;
    int e = er >> 4, r = er & 15;
    v = lA[((long)e * DK + k) * NR + r];
  }
  RA[idx] = f2bf(v);
}

// BT[n][kp] = lora_B[kp/16][kp%16][n]  -> [DN][128] bf16
__global__ void k_build_bt(const float* __restrict__ lB, unsigned short* __restrict__ BT) {
  int idx = blockIdx.x * 256 + threadIdx.x;
  if (idx >= DN * ERC) return;
  int n = idx >> 7;
  int kp = idx & 127;
  BT[idx] = f2bf(lB[(long)kp * DN + n]);
}

// ---------- fused small kernel -----------------------------------------------
// Per 64-token block: (1) read x f32, convert -> write Xb global AND stage LDS;
// (2) GEMM vs RA -> H[64][160] (router logits + lora h) kept in LDS;
// (3) sparsemax per token; (4) write G[t][er] = w_e * h_er as bf16.
// Replaces the separate k_cvt(x) + k_gemm_small + k_router (saves 134MB traffic
// + 2 launches; H never touches global memory).
__global__ __launch_bounds__(256, 2)
void k_small_fused(const float* __restrict__ x, const unsigned short* __restrict__ RA,
                   unsigned short* __restrict__ Xb, const float* __restrict__ b_router,
                   unsigned short* __restrict__ Gout) {
  __shared__ unsigned short At[64 * 64];
  __shared__ unsigned short Bt[RAC * 64];
  __shared__ float Hl[64][160];
  __shared__ float Wl[64][NE];
  int m0 = blockIdx.x * 64;
  int tid = threadIdx.x;
  int lane = tid & 63, wid = tid >> 6;
  int wr = wid >> 1, wc = wid & 1;      // 2x2 waves; wave tile 32 x 80
  int l16 = lane & 15, lhi = lane >> 4;
  f32x4 acc[2][5] = {};
  int row = tid >> 2, c16 = (tid & 3) * 16;
  int byteoff = tid * 16;
  for (int k0 = 0; k0 < DK; k0 += 64) {
    // ---- X: f32 read -> bf16 convert -> Xb global write + LDS stage ----
    const float* xs = x + (long)(m0 + row) * DK + k0 + c16;
    float4 v0 = *(const float4*)(xs);
    float4 v1 = *(const float4*)(xs + 4);
    float4 v2 = *(const float4*)(xs + 8);
    float4 v3 = *(const float4*)(xs + 12);
    bfrag lo, hi;
    lo[0] = (short)f2bf(v0.x); lo[1] = (short)f2bf(v0.y);
    lo[2] = (short)f2bf(v0.z); lo[3] = (short)f2bf(v0.w);
    lo[4] = (short)f2bf(v1.x); lo[5] = (short)f2bf(v1.y);
    lo[6] = (short)f2bf(v1.z); lo[7] = (short)f2bf(v1.w);
    hi[0] = (short)f2bf(v2.x); hi[1] = (short)f2bf(v2.y);
    hi[2] = (short)f2bf(v2.z); hi[3] = (short)f2bf(v2.w);
    hi[4] = (short)f2bf(v3.x); hi[5] = (short)f2bf(v3.y);
    hi[6] = (short)f2bf(v3.z); hi[7] = (short)f2bf(v3.w);
    unsigned short* xb = Xb + (long)(m0 + row) * DK + k0 + c16;
    *(bfrag*)xb = lo;
    *(bfrag*)(xb + 8) = hi;
    *(bfrag*)&At[row * 64 + c16] = lo;
    *(bfrag*)&At[row * 64 + c16 + 8] = hi;
    // ---- RA staging (unchanged): global_load_lds x5 ----
#pragma unroll
    for (int r = 0; r < 5; r++) {
      int off = r * 4096 + byteoff;
      int rrow = off >> 7, colb = off & 127;
      load_lds16((const char*)RA + ((long)rrow * DK + k0) * 2 + colb, (char*)Bt + off);
    }
    __syncthreads();
#pragma unroll
    for (int kk = 0; kk < 2; kk++) {
      bfrag a[2], b[5];
#pragma unroll
      for (int m = 0; m < 2; m++)
        a[m] = *(const bfrag*)&At[(wr * 32 + m * 16 + l16) * 64 + kk * 32 + lhi * 8];
#pragma unroll
      for (int n = 0; n < 5; n++)
        b[n] = *(const bfrag*)&Bt[(wc * 80 + n * 16 + l16) * 64 + kk * 32 + lhi * 8];
#pragma unroll
      for (int m = 0; m < 2; m++)
#pragma unroll
        for (int n = 0; n < 5; n++)
          acc[m][n] = __builtin_amdgcn_mfma_f32_16x16x32_bf16(a[m], b[n], acc[m][n], 0, 0, 0);
    }
    __syncthreads();
  }
  // ---- epilogue: acc -> Hl (LDS) ----
#pragma unroll
  for (int m = 0; m < 2; m++)
#pragma unroll
    for (int n = 0; n < 5; n++) {
      int col = wc * 80 + n * 16 + l16;
      int trow = wr * 32 + m * 16 + lhi * 4;
#pragma unroll
      for (int j = 0; j < 4; j++)
        Hl[trow + j][col] = acc[m][n][j];
    }
  __syncthreads();
  // ---- sparsemax per token (threads 0..63) ----
  if (tid < 64) {
    float z[NE], zs[NE];
#pragma unroll
    for (int e = 0; e < NE; e++) { z[e] = Hl[tid][e] + b_router[e]; zs[e] = z[e]; }
#pragma unroll
    for (int i = 1; i < NE; i++) {
      float key = zs[i];
      int j = i - 1;
      while (j >= 0 && zs[j] < key) { zs[j + 1] = zs[j]; j--; }
      zs[j + 1] = key;
    }
    float cums[NE];
    float cum = 0.f;
#pragma unroll
    for (int j = 0; j < NE; j++) { cum += zs[j]; cums[j] = cum; }
    int kz = 0;
#pragma unroll
    for (int j = 0; j < NE; j++)
      if (1.f + (float)(j + 1) * zs[j] > cums[j]) kz = j + 1;
    float tau = (cums[kz - 1] - 1.f) / (float)kz;
#pragma unroll
    for (int e = 0; e < NE; e++)
      Wl[tid][e] = fmaxf(z[e] - tau, 0.f);
  }
  __syncthreads();
  // ---- write G = w_e * h (bf16), cooperatively ----
  for (int idx = tid; idx < 64 * ERC; idx += 256) {
    int tk = idx >> 7, er = idx & 127;
    Gout[(long)(m0 + tk) * ERC + er] = f2bf(Wl[tk][er >> 4] * Hl[tk][NE + er]);
  }
}

// ---------- main GEMM: 256x256 tile, BK=32, 4-deep ring, m201 phase rhythm ----
// (R5 known-good: 542us, MfmaUtil 46.4%, 0 bank conflicts -- unchanged)
// out = Xb @ Wb^T + bias + G @ BT^T, fused as 128 + 4 K-tiles of 32.
// Per phase: {issue ds_reads -> issue stage -> s_barrier -> lgkmcnt(0) ->
// setprio(1) 16xMFMA setprio(0)}; boundary vmcnt(8)+barrier once per K-tile
// (counted: stages for t+2,t+3 are the 8 newest outstanding -> certifies t+1).
// T2 swizzle (rule #21 both-sides): source slot pre-permuted by
// ((tid&3)^((tid>>3)&3)); read slot = lhi ^ ((l16>>1)&3). Conflict-free.
struct KtArgs {
  const unsigned short *pXA0, *pXA1, *pWB0, *pWB1, *pGA0, *pGA1, *pTB0, *pTB1;
  int soffA0, soffA1, soffB0, soffB1;   // element offsets within a ring slot
  int wr, wc, l16, swslot;              // swslot in shorts
};

template<bool STAGE, int VMB>
__device__ __forceinline__ void ktile_body(int t, unsigned short* lds, const KtArgs& A,
                                           f32x4 (&acc)[8][4]) {
  unsigned short* s = lds + (t & 3) * 16384;
  bfrag bfr[4], al[4], ah[4];
  // ---- phase 0: issue reads (B-frags + A-lo), issue A-stage(t+3) ----
#pragma unroll
  for (int n = 0; n < 4; n++)
    bfr[n] = *(const bfrag*)&s[8192 + (A.wc * 64 + n * 16 + A.l16) * 32 + A.swslot];
#pragma unroll
  for (int m = 0; m < 4; m++)
    al[m] = *(const bfrag*)&s[(A.wr * 128 + m * 16 + A.l16) * 32 + A.swslot];
  if constexpr (STAGE) {
    int u = t + 3;
    unsigned short* d = lds + (u & 3) * 16384;
    if (u < NT_MAIN) {
      load_lds16(A.pXA0 + (long)u * 32, d + A.soffA0);
      load_lds16(A.pXA1 + (long)u * 32, d + A.soffA1);
    } else {
      long v = u - NT_MAIN;
      load_lds16(A.pGA0 + v * 32, d + A.soffA0);
      load_lds16(A.pGA1 + v * 32, d + A.soffA1);
    }
  }
  // barrier first (arrival skew overlaps LDS drain), then cheap lgkm0
  asm volatile("s_barrier\n\ts_waitcnt lgkmcnt(0)" ::: "memory");
  __builtin_amdgcn_sched_barrier(0);            // rule #18: pin MFMA after wait
  __builtin_amdgcn_s_setprio(1);
#pragma unroll
  for (int m = 0; m < 4; m++)
#pragma unroll
    for (int n = 0; n < 4; n++)
      acc[m][n] = __builtin_amdgcn_mfma_f32_16x16x32_bf16(al[m], bfr[n], acc[m][n], 0, 0, 0);
  __builtin_amdgcn_s_setprio(0);
  // ---- phase 1: issue reads (A-hi), issue B-stage(t+3) ----
#pragma unroll
  for (int m = 0; m < 4; m++)
    ah[m] = *(const bfrag*)&s[(A.wr * 128 + 64 + m * 16 + A.l16) * 32 + A.swslot];
  if constexpr (STAGE) {
    int u = t + 3;
    unsigned short* d = lds + (u & 3) * 16384;
    if (u < NT_MAIN) {
      load_lds16(A.pWB0 + (long)u * 32, d + A.soffB0);
      load_lds16(A.pWB1 + (long)u * 32, d + A.soffB1);
    } else {
      long v = u - NT_MAIN;
      load_lds16(A.pTB0 + v * 32, d + A.soffB0);
      load_lds16(A.pTB1 + v * 32, d + A.soffB1);
    }
  }
  asm volatile("s_barrier\n\ts_waitcnt lgkmcnt(0)" ::: "memory");
  __builtin_amdgcn_sched_barrier(0);
  __builtin_amdgcn_s_setprio(1);
#pragma unroll
  for (int m = 0; m < 4; m++)
#pragma unroll
    for (int n = 0; n < 4; n++)
      acc[4 + m][n] = __builtin_amdgcn_mfma_f32_16x16x32_bf16(ah[m], bfr[n], acc[4 + m][n], 0, 0, 0);
  __builtin_amdgcn_s_setprio(0);
  // ---- boundary: certify slot t+1 for next body's pre-barrier reads ----
  if constexpr (VMB == 8)      asm volatile("s_waitcnt vmcnt(8)\n\ts_barrier" ::: "memory");
  else if constexpr (VMB == 4) asm volatile("s_waitcnt vmcnt(4)\n\ts_barrier" ::: "memory");
  else if constexpr (VMB == 0) asm volatile("s_waitcnt vmcnt(0)\n\ts_barrier" ::: "memory");
  // VMB < 0: last tile, no boundary needed
}

__global__ __launch_bounds__(512, 2)
void k_gemm_main(const unsigned short* __restrict__ X, const unsigned short* __restrict__ W,
                 const unsigned short* __restrict__ G, const unsigned short* __restrict__ BT,
                 const float* __restrict__ bias, float* __restrict__ out) {
  // 4 ring slots x (A[256][32] + B[256][32]) bf16 = 4 x 32 KiB = 128 KiB
  __shared__ unsigned short lds[4 * 16384];
  int bid = blockIdx.x;
  // XCD-aware swizzle: 1024 workgroups, 8 XCDs -> contiguous chunks of 128 per XCD
  int swz = (bid & 7) * 128 + (bid >> 3);
  int bm = swz >> 4, bn = swz & 15;
  int m0 = bm * 256, n0 = bn * 256;
  int tid = threadIdx.x;
  int lane = tid & 63, wid = tid >> 6;

  KtArgs A;
  A.wr = wid >> 2; A.wc = wid & 3;      // 2x4 waves; wave tile 128 x 64
  A.l16 = lane & 15;
  int lhi = lane >> 4;
  A.swslot = (lhi ^ ((A.l16 >> 1) & 3)) * 8;      // read-side swizzle (shorts)
  // staging: thread tid owns LDS (row=tid>>2, slot=tid&3); source slot pre-swizzled
  int r0 = tid >> 2;
  int c8 = (((tid & 3) ^ ((tid >> 3) & 3)) * 8);  // swizzled source column (shorts)
  A.pXA0 = X + (long)(m0 + r0) * DK + c8;
  A.pXA1 = X + (long)(m0 + 128 + r0) * DK + c8;
  A.pWB0 = W + (long)(n0 + r0) * DK + c8;
  A.pWB1 = W + (long)(n0 + 128 + r0) * DK + c8;
  A.pGA0 = G + (long)(m0 + r0) * ERC + c8;
  A.pGA1 = G + (long)(m0 + 128 + r0) * ERC + c8;
  A.pTB0 = BT + (long)(n0 + r0) * ERC + c8;
  A.pTB1 = BT + (long)(n0 + 128 + r0) * ERC + c8;
  A.soffA0 = tid * 8;
  A.soffA1 = 4096 + tid * 8;
  A.soffB0 = 8192 + tid * 8;
  A.soffB1 = 12288 + tid * 8;

  f32x4 acc[8][4] = {};

  // prologue: stage tiles 0,1,2 (all base-path); certify slot 0
#pragma unroll
  for (int u = 0; u < 3; u++) {
    unsigned short* d = lds + u * 16384;
    load_lds16(A.pXA0 + (long)u * 32, d + A.soffA0);
    load_lds16(A.pXA1 + (long)u * 32, d + A.soffA1);
    load_lds16(A.pWB0 + (long)u * 32, d + A.soffB0);
    load_lds16(A.pWB1 + (long)u * 32, d + A.soffB1);
  }
  asm volatile("s_waitcnt vmcnt(8)\n\ts_barrier" ::: "memory");

  for (int t = 0; t <= 128; t++)
    ktile_body<true, 8>(t, lds, A, acc);
  ktile_body<false, 4>(129, lds, A, acc);
  ktile_body<false, 0>(130, lds, A, acc);
  ktile_body<false, -1>(131, lds, A, acc);

  // epilogue: bias + f32 store
#pragma unroll
  for (int n = 0; n < 4; n++) {
    int col = n0 + A.wc * 64 + n * 16 + A.l16;
    float bv = bias[col];
#pragma unroll
    for (int m = 0; m < 8; m++) {
      int row = m0 + A.wr * 128 + m * 16 + lhi * 4;
#pragma unroll
      for (int j = 0; j < 4; j++)
        out[(long)(row + j) * DN + col] = acc[m][n][j] + bv;
    }
  }
}

extern "C" void kernel_launch(void* const* d_in, const int* in_sizes, int n_in,
                              void* d_out, int out_size, void* d_ws, size_t ws_size,
                              hipStream_t stream) {
  const float* x        = (const float*)d_in[0];
  const float* W_base   = (const float*)d_in[1];
  const float* b_base   = (const float*)d_in[2];
  const float* W_router = (const float*)d_in[3];
  const float* b_router = (const float*)d_in[4];
  const float* lora_A   = (const float*)d_in[5];
  const float* lora_B   = (const float*)d_in[6];
  float* out = (float*)d_out;

  char* ws = (char*)d_ws;
  unsigned short* Xb = (unsigned short*)ws;                       // 134217728 B
  unsigned short* Wb = (unsigned short*)(ws + 134217728L);        // 33554432 B
  unsigned short* RA = (unsigned short*)(ws + 167772160L);        // 1310720 B
  unsigned short* BT = (unsigned short*)(ws + 169082880L);        // 1048576 B
  unsigned short* G  = (unsigned short*)(ws + 180617216L);        // 4194304 B

  hipLaunchKernelGGL(k_cvt, dim3(2048), dim3(256), 0, stream, W_base, Wb, (long)DN * DK / 4);
  hipLaunchKernelGGL(k_build_ra, dim3((RAC * DK + 255) / 256), dim3(256), 0, stream,
                     W_router, lora_A, RA);
  hipLaunchKernelGGL(k_build_bt, dim3((DN * ERC + 255) / 256), dim3(256), 0, stream, lora_B, BT);
  // fused: x->bf16 (writes Xb) + router logits/h GEMM + sparsemax + G
  hipLaunchKernelGGL(k_small_fused, dim3(M_TOK / 64), dim3(256), 0, stream,
                     x, RA, Xb, b_router, G);
  // main fused GEMM (R5 known-good)
  hipLaunchKernelGGL(k_gemm_main, dim3((M_TOK / 256) * (DN / 256)), dim3(512), 0, stream,
                     Xb, Wb, G, BT, b_base, out);
}

// Round 10
// 634.380 us; speedup vs baseline: 1.4263x; 1.0625x over previous
//
#include <hip/hip_runtime.h>
#include <hip/hip_bf16.h>

// Problem constants (fixed by reference setup_inputs)
#define M_TOK 16384   // B*S = 8*2048
#define DK    4096    // D_IN
#define DN    4096    // D_OUT
#define NE    8       // experts
#define NR    16      // lora rank
#define ERC   128     // E*R
#define RAC   160     // padded router+A columns (8 + 128 + 24 pad)
#define NT64  66      // K-tiles of 64: 64 base + 2 expert

typedef __attribute__((ext_vector_type(8))) short bfrag;   // 8 bf16 (4 VGPRs)
typedef __attribute__((ext_vector_type(4))) float f32x4;   // MFMA acc

__device__ __forceinline__ unsigned short f2bf(float f) {
  unsigned u = __builtin_bit_cast(unsigned, f);
  unsigned rounding = 0x7FFFu + ((u >> 16) & 1u);
  u += rounding;
  return (unsigned short)(u >> 16);
}

__device__ __forceinline__ void load_lds16(const void* g, void* l) {
  __builtin_amdgcn_global_load_lds(
      (__attribute__((address_space(1))) void*)(g),
      (__attribute__((address_space(3))) void*)(l), 16, 0, 0);
}

// ---------- conversion kernels ----------
__global__ void k_cvt(const float* __restrict__ in, unsigned short* __restrict__ out, long n4) {
  long i = (long)blockIdx.x * blockDim.x + threadIdx.x;
  long stride = (long)gridDim.x * blockDim.x;
  for (; i < n4; i += stride) {
    float4 v = reinterpret_cast<const float4*>(in)[i];
    ushort4 o;
    o.x = f2bf(v.x); o.y = f2bf(v.y); o.z = f2bf(v.z); o.w = f2bf(v.w);
    reinterpret_cast<ushort4*>(out)[i] = o;
  }
}

// RA[c][k], c in [0,160): c<8 -> W_router[c][k]; 8<=c<136 -> lora_A[e][k][r]; pad 0
__global__ void k_build_ra(const float* __restrict__ Wr, const float* __restrict__ lA,
                           unsigned short* __restrict__ RA) {
  int idx = blockIdx.x * 256 + threadIdx.x;
  if (idx >= RAC * DK) return;
  int c = idx >> 12;          // /4096
  int k = idx & (DK - 1);
  float v = 0.f;
  if (c < NE) {
    v = Wr[c * DK + k];
  } else if (c < NE + ERC) {
    int er = c - NE;
    int e = er >> 4, r = er & 15;
    v = lA[((long)e * DK + k) * NR + r];
  }
  RA[idx] = f2bf(v);
}

// BT[n][kp] = lora_B[kp/16][kp%16][n]  -> [DN][128] bf16
__global__ void k_build_bt(const float* __restrict__ lB, unsigned short* __restrict__ BT) {
  int idx = blockIdx.x * 256 + threadIdx.x;
  if (idx >= DN * ERC) return;
  int n = idx >> 7;
  int kp = idx & 127;
  BT[idx] = f2bf(lB[(long)kp * DN + n]);
}

// ---------- fused small kernel (R9 proven) -----------------------------------
// Per 64-token block: x f32 -> bf16 (write Xb + stage LDS); GEMM vs RA -> H in
// LDS; sparsemax; write G = w_e * h as bf16.
__global__ __launch_bounds__(256, 2)
void k_small_fused(const float* __restrict__ x, const unsigned short* __restrict__ RA,
                   unsigned short* __restrict__ Xb, const float* __restrict__ b_router,
                   unsigned short* __restrict__ Gout) {
  __shared__ unsigned short At[64 * 64];
  __shared__ unsigned short Bt[RAC * 64];
  __shared__ float Hl[64][160];
  __shared__ float Wl[64][NE];
  int m0 = blockIdx.x * 64;
  int tid = threadIdx.x;
  int lane = tid & 63, wid = tid >> 6;
  int wr = wid >> 1, wc = wid & 1;      // 2x2 waves; wave tile 32 x 80
  int l16 = lane & 15, lhi = lane >> 4;
  f32x4 acc[2][5] = {};
  int row = tid >> 2, c16 = (tid & 3) * 16;
  int byteoff = tid * 16;
  for (int k0 = 0; k0 < DK; k0 += 64) {
    const float* xs = x + (long)(m0 + row) * DK + k0 + c16;
    float4 v0 = *(const float4*)(xs);
    float4 v1 = *(const float4*)(xs + 4);
    float4 v2 = *(const float4*)(xs + 8);
    float4 v3 = *(const float4*)(xs + 12);
    bfrag lo, hi;
    lo[0] = (short)f2bf(v0.x); lo[1] = (short)f2bf(v0.y);
    lo[2] = (short)f2bf(v0.z); lo[3] = (short)f2bf(v0.w);
    lo[4] = (short)f2bf(v1.x); lo[5] = (short)f2bf(v1.y);
    lo[6] = (short)f2bf(v1.z); lo[7] = (short)f2bf(v1.w);
    hi[0] = (short)f2bf(v2.x); hi[1] = (short)f2bf(v2.y);
    hi[2] = (short)f2bf(v2.z); hi[3] = (short)f2bf(v2.w);
    hi[4] = (short)f2bf(v3.x); hi[5] = (short)f2bf(v3.y);
    hi[6] = (short)f2bf(v3.z); hi[7] = (short)f2bf(v3.w);
    unsigned short* xb = Xb + (long)(m0 + row) * DK + k0 + c16;
    *(bfrag*)xb = lo;
    *(bfrag*)(xb + 8) = hi;
    *(bfrag*)&At[row * 64 + c16] = lo;
    *(bfrag*)&At[row * 64 + c16 + 8] = hi;
#pragma unroll
    for (int r = 0; r < 5; r++) {
      int off = r * 4096 + byteoff;
      int rrow = off >> 7, colb = off & 127;
      load_lds16((const char*)RA + ((long)rrow * DK + k0) * 2 + colb, (char*)Bt + off);
    }
    __syncthreads();
#pragma unroll
    for (int kk = 0; kk < 2; kk++) {
      bfrag a[2], b[5];
#pragma unroll
      for (int m = 0; m < 2; m++)
        a[m] = *(const bfrag*)&At[(wr * 32 + m * 16 + l16) * 64 + kk * 32 + lhi * 8];
#pragma unroll
      for (int n = 0; n < 5; n++)
        b[n] = *(const bfrag*)&Bt[(wc * 80 + n * 16 + l16) * 64 + kk * 32 + lhi * 8];
#pragma unroll
      for (int m = 0; m < 2; m++)
#pragma unroll
        for (int n = 0; n < 5; n++)
          acc[m][n] = __builtin_amdgcn_mfma_f32_16x16x32_bf16(a[m], b[n], acc[m][n], 0, 0, 0);
    }
    __syncthreads();
  }
#pragma unroll
  for (int m = 0; m < 2; m++)
#pragma unroll
    for (int n = 0; n < 5; n++) {
      int col = wc * 80 + n * 16 + l16;
      int trow = wr * 32 + m * 16 + lhi * 4;
#pragma unroll
      for (int j = 0; j < 4; j++)
        Hl[trow + j][col] = acc[m][n][j];
    }
  __syncthreads();
  if (tid < 64) {
    float z[NE], zs[NE];
#pragma unroll
    for (int e = 0; e < NE; e++) { z[e] = Hl[tid][e] + b_router[e]; zs[e] = z[e]; }
#pragma unroll
    for (int i = 1; i < NE; i++) {
      float key = zs[i];
      int j = i - 1;
      while (j >= 0 && zs[j] < key) { zs[j + 1] = zs[j]; j--; }
      zs[j + 1] = key;
    }
    float cums[NE];
    float cum = 0.f;
#pragma unroll
    for (int j = 0; j < NE; j++) { cum += zs[j]; cums[j] = cum; }
    int kz = 0;
#pragma unroll
    for (int j = 0; j < NE; j++)
      if (1.f + (float)(j + 1) * zs[j] > cums[j]) kz = j + 1;
    float tau = (cums[kz - 1] - 1.f) / (float)kz;
#pragma unroll
    for (int e = 0; e < NE; e++)
      Wl[tid][e] = fmaxf(z[e] - tau, 0.f);
  }
  __syncthreads();
  for (int idx = tid; idx < 64 * ERC; idx += 256) {
    int tk = idx >> 7, er = idx & 127;
    Gout[(long)(m0 + tk) * ERC + er] = f2bf(Wl[tk][er >> 4] * Hl[tk][NE + er]);
  }
}

// ---------- main GEMM: 8-phase 256x256, BK=64, fused expert (R8 + race fix) --
// out = Xb @ Wb^T + bias + G @ BT^T as 66 K-tiles of 64 (64 base + 2 expert).
// LDS 128 KiB: A,B each [2 dbuf][2 TILE-half (rows 0-127 / 128-255)][128][64].
// 8 waves 2Mx4N; wave wr reads A tile-half wr (al rows 0-63 in ph0, ah rows
// 64-127 in ph2); wave wc reads B tile-half wc>>1 in ph0 (bl) + ph1 (bh).
// R8 BUG (fixed): A-h0(t+2) was staged in ph1 -> dbuf t&1, overwriting the
// region wr=0 waves read as ah IN PH2 of tile t (stage landed mid-read ->
// systematic corruption of output rows 64-127 per 256-tile, absmax 7.8).
// Corrected stage schedule (each region staged only AFTER its last read phase
// has passed a barrier; t+1 stages go to the opposite dbuf, always safe):
//   ph0: A-h1(t+1) | ph1: none | ph2: B-h0(t+2) | ph3: B-h1(t+2), A-h0(t+2)
// Boundary vmcnt(6)+barrier once per K-tile: per-tile issue order is
// [A-h1(t+1) x2][B-h0(t+2) x2][B-h1(t+2) x2][A-h0(t+2) x2]; keeping the newest
// 6 in flight drains A-h1(t+1) and all older -> tile t+1 fully certified.
// Bank swizzle (rule #21 both-sides): stored granule = logical ^ (row&7);
// read phys = (kk*4+lhi) ^ (l16&7); source col slot = (tid&7) ^ ((tid>>3)&7).
struct KtArgs {
  const unsigned short *pX, *pW, *pG, *pT;
  int aB, bB, sw0, sw1, tid8;
};

__device__ __forceinline__ void stage_half(unsigned short* lds, const KtArgs& A,
                                           int u, int arr, int h) {
  unsigned short* dst = lds + arr * 32768 + (u & 1) * 16384 + h * 8192 + A.tid8;
  if (u < 64) {
    const unsigned short* s = (arr ? A.pW : A.pX) + (long)(h * 128) * DK + (long)u * 64;
    load_lds16(s, dst);
    load_lds16(s + (long)64 * DK, dst + 4096);
  } else {
    const unsigned short* s = (arr ? A.pT : A.pG) + (long)(h * 128) * ERC + (long)(u - 64) * 64;
    load_lds16(s, dst);
    load_lds16(s + (long)64 * ERC, dst + 4096);
  }
}

template<bool AHI, bool T2, int VMB>
__device__ __forceinline__ void ktile(int t, unsigned short* lds, const KtArgs& A,
                                      f32x4 (&acc)[8][4]) {
  unsigned short* L = lds + (t & 1) * 16384;
  bfrag bl[4], bh[4], al[8], ah[8];
  // ---- ph0: read b_lo(4) + a_lo(8); stage A-h1(t+1) [opposite dbuf] ----
#pragma unroll
  for (int nf = 0; nf < 2; nf++)
#pragma unroll
    for (int kk = 0; kk < 2; kk++)
      bl[nf * 2 + kk] = *(const bfrag*)&L[A.bB + nf * 1024 + (kk ? A.sw1 : A.sw0)];
#pragma unroll
  for (int f = 0; f < 4; f++)
#pragma unroll
    for (int kk = 0; kk < 2; kk++)
      al[f * 2 + kk] = *(const bfrag*)&L[A.aB + f * 1024 + (kk ? A.sw1 : A.sw0)];
  if constexpr (AHI) stage_half(lds, A, t + 1, 0, 1);
  asm volatile("s_waitcnt lgkmcnt(8)" ::: "memory");
  __builtin_amdgcn_s_barrier();
  asm volatile("s_waitcnt lgkmcnt(0)" ::: "memory");
  __builtin_amdgcn_sched_barrier(0);
  __builtin_amdgcn_s_setprio(1);
#pragma unroll
  for (int f = 0; f < 4; f++)
#pragma unroll
    for (int nf = 0; nf < 2; nf++)
#pragma unroll
      for (int kk = 0; kk < 2; kk++)
        acc[f][nf] = __builtin_amdgcn_mfma_f32_16x16x32_bf16(al[f * 2 + kk], bl[nf * 2 + kk], acc[f][nf], 0, 0, 0);
  __builtin_amdgcn_s_setprio(0);
  __builtin_amdgcn_s_barrier();
  // ---- ph1: read b_hi(4); NO stage (fix); Q(lo,hi) ----
#pragma unroll
  for (int nf = 0; nf < 2; nf++)
#pragma unroll
    for (int kk = 0; kk < 2; kk++)
      bh[nf * 2 + kk] = *(const bfrag*)&L[A.bB + (2 + nf) * 1024 + (kk ? A.sw1 : A.sw0)];
  __builtin_amdgcn_s_barrier();
  asm volatile("s_waitcnt lgkmcnt(0)" ::: "memory");
  __builtin_amdgcn_sched_barrier(0);
  __builtin_amdgcn_s_setprio(1);
#pragma unroll
  for (int f = 0; f < 4; f++)
#pragma unroll
    for (int nf = 0; nf < 2; nf++)
#pragma unroll
      for (int kk = 0; kk < 2; kk++)
        acc[f][2 + nf] = __builtin_amdgcn_mfma_f32_16x16x32_bf16(al[f * 2 + kk], bh[nf * 2 + kk], acc[f][2 + nf], 0, 0, 0);
  __builtin_amdgcn_s_setprio(0);
  __builtin_amdgcn_s_barrier();
  // ---- ph2: read a_hi(8); stage B-h0(t+2) [B-h0 last read was ph1]; Q(hi,lo) ----
#pragma unroll
  for (int f = 0; f < 4; f++)
#pragma unroll
    for (int kk = 0; kk < 2; kk++)
      ah[f * 2 + kk] = *(const bfrag*)&L[A.aB + (4 + f) * 1024 + (kk ? A.sw1 : A.sw0)];
  if constexpr (T2) stage_half(lds, A, t + 2, 1, 0);
  __builtin_amdgcn_s_barrier();
  asm volatile("s_waitcnt lgkmcnt(0)" ::: "memory");
  __builtin_amdgcn_sched_barrier(0);
  __builtin_amdgcn_s_setprio(1);
#pragma unroll
  for (int f = 0; f < 4; f++)
#pragma unroll
    for (int nf = 0; nf < 2; nf++)
#pragma unroll
      for (int kk = 0; kk < 2; kk++)
        acc[4 + f][nf] = __builtin_amdgcn_mfma_f32_16x16x32_bf16(ah[f * 2 + kk], bl[nf * 2 + kk], acc[4 + f][nf], 0, 0, 0);
  __builtin_amdgcn_s_setprio(0);
  __builtin_amdgcn_s_barrier();
  // ---- ph3: no reads; stage B-h1(t+2) + A-h0(t+2) [last reads ph1/ph2]; Q(hi,hi) ----
  if constexpr (T2) {
    stage_half(lds, A, t + 2, 1, 1);
    stage_half(lds, A, t + 2, 0, 0);
  }
  __builtin_amdgcn_s_setprio(1);
#pragma unroll
  for (int f = 0; f < 4; f++)
#pragma unroll
    for (int nf = 0; nf < 2; nf++)
#pragma unroll
      for (int kk = 0; kk < 2; kk++)
        acc[4 + f][2 + nf] = __builtin_amdgcn_mfma_f32_16x16x32_bf16(ah[f * 2 + kk], bh[nf * 2 + kk], acc[4 + f][2 + nf], 0, 0, 0);
  __builtin_amdgcn_s_setprio(0);
  if constexpr (VMB == 6)      asm volatile("s_waitcnt vmcnt(6)\n\ts_barrier" ::: "memory");
  else if constexpr (VMB == 0) asm volatile("s_waitcnt vmcnt(0)\n\ts_barrier" ::: "memory");
  // VMB < 0: last tile, no boundary
}

__global__ __launch_bounds__(512, 2)
void k_gemm_main(const unsigned short* __restrict__ X, const unsigned short* __restrict__ W,
                 const unsigned short* __restrict__ G, const unsigned short* __restrict__ BT,
                 const float* __restrict__ bias, float* __restrict__ out) {
  // A: [2 dbuf][2 half][128][64] at 0; B: same at 32768 (shorts). 128 KiB total.
  __shared__ unsigned short lds[65536];
  int bid = blockIdx.x;
  // XCD-aware swizzle: 1024 workgroups, 8 XCDs -> contiguous chunks of 128
  int swz = (bid & 7) * 128 + (bid >> 3);
  int bm = swz >> 4, bn = swz & 15;
  int m0 = bm * 256, n0 = bn * 256;
  int tid = threadIdx.x;
  int lane = tid & 63, wid = tid >> 6;
  int wr = wid >> 2, wc = wid & 3;      // 2x4 waves; wave tile 128 x 64
  int l16 = lane & 15, lhi = lane >> 4;

  KtArgs A;
  A.sw0 = (lhi ^ (l16 & 7)) * 8;
  A.sw1 = ((4 + lhi) ^ (l16 & 7)) * 8;
  A.aB = wr * 8192 + l16 * 64;
  A.bB = 32768 + (wc >> 1) * 8192 + ((wc & 1) * 64 + l16) * 64;
  A.tid8 = tid * 8;
  int swz8 = ((tid & 7) ^ ((tid >> 3) & 7)) * 8;    // pre-swizzled source slot
  int r0 = tid >> 3;
  A.pX = X + (long)(m0 + r0) * DK + swz8;
  A.pW = W + (long)(n0 + r0) * DK + swz8;
  A.pG = G + (long)(m0 + r0) * ERC + swz8;
  A.pT = BT + (long)(n0 + r0) * ERC + swz8;

  f32x4 acc[8][4] = {};

  // prologue: tile0 all 4 halves, then tile1 {A-h0, B-h0, B-h1} (A-h1(1) comes
  // from tile 0's ph0). vmcnt(6) -> tile 0's 8 oldest loads drained.
  stage_half(lds, A, 0, 0, 0);
  stage_half(lds, A, 0, 1, 0);
  stage_half(lds, A, 0, 1, 1);
  stage_half(lds, A, 0, 0, 1);
  stage_half(lds, A, 1, 0, 0);
  stage_half(lds, A, 1, 1, 0);
  stage_half(lds, A, 1, 1, 1);
  asm volatile("s_waitcnt vmcnt(6)\n\ts_barrier" ::: "memory");

  for (int t = 0; t < 64; t++)
    ktile<true, true, 6>(t, lds, A, acc);
  ktile<true, false, 0>(64, lds, A, acc);
  ktile<false, false, -1>(65, lds, A, acc);

  // epilogue: bias + f32 store
#pragma unroll
  for (int nf = 0; nf < 4; nf++) {
    int col = n0 + wc * 64 + nf * 16 + l16;
    float bv = bias[col];
#pragma unroll
    for (int f = 0; f < 8; f++) {
      int row = m0 + wr * 128 + f * 16 + lhi * 4;
#pragma unroll
      for (int j = 0; j < 4; j++)
        out[(long)(row + j) * DN + col] = acc[f][nf][j] + bv;
    }
  }
}

extern "C" void kernel_launch(void* const* d_in, const int* in_sizes, int n_in,
                              void* d_out, int out_size, void* d_ws, size_t ws_size,
                              hipStream_t stream) {
  const float* x        = (const float*)d_in[0];
  const float* W_base   = (const float*)d_in[1];
  const float* b_base   = (const float*)d_in[2];
  const float* W_router = (const float*)d_in[3];
  const float* b_router = (const float*)d_in[4];
  const float* lora_A   = (const float*)d_in[5];
  const float* lora_B   = (const float*)d_in[6];
  float* out = (float*)d_out;

  char* ws = (char*)d_ws;
  unsigned short* Xb = (unsigned short*)ws;                       // 134217728 B
  unsigned short* Wb = (unsigned short*)(ws + 134217728L);        // 33554432 B
  unsigned short* RA = (unsigned short*)(ws + 167772160L);        // 1310720 B
  unsigned short* BT = (unsigned short*)(ws + 169082880L);        // 1048576 B
  unsigned short* G  = (unsigned short*)(ws + 180617216L);        // 4194304 B

  hipLaunchKernelGGL(k_cvt, dim3(2048), dim3(256), 0, stream, W_base, Wb, (long)DN * DK / 4);
  hipLaunchKernelGGL(k_build_ra, dim3((RAC * DK + 255) / 256), dim3(256), 0, stream,
                     W_router, lora_A, RA);
  hipLaunchKernelGGL(k_build_bt, dim3((DN * ERC + 255) / 256), dim3(256), 0, stream, lora_B, BT);
  // fused: x->bf16 (writes Xb) + router logits/h GEMM + sparsemax + G
  hipLaunchKernelGGL(k_small_fused, dim3(M_TOK / 64), dim3(256), 0, stream,
                     x, RA, Xb, b_router, G);
  // main fused GEMM (8-phase, race-fixed)
  hipLaunchKernelGGL(k_gemm_main, dim3((M_TOK / 256) * (DN / 256)), dim3(512), 0, stream,
                     Xb, Wb, G, BT, b_base, out);
}